// Round 10
// baseline (2279.167 us; speedup 1.0000x reference)
//
#include <hip/hip_runtime.h>

// Problem constants (from reference): B=256, NSEL=60000, NVERTS=100000, F=3
#define B_C      256
#define NSEL_C   60000
#define NV_C     100000
#define NBLK_P   ((NSEL_C + 255) / 256)   // 235 row-blocks per batch

// ---------------- zero via agent-scope stores (MALL-allocating) ----------------
// R7/R8/R6 triangulation: scatter atomics are fast ONLY when out lines are
// L3/MALL-resident (R6 fillBuffer: ~520 G atomics/s) and catastrophically slow
// when lines are MALL-absent (R8 NT zero -> DRAM-side 32B RMW, 1.44 GB writes,
// 20 G/s) or dirty in per-XCD L2 (R7 cached zero). Agent-scope relaxed atomic
// stores emit global_store_dwordx2 with system-coherence bits: bypass L1/L2
// and land in the MALL, leaving lines resident there for the atomics.
__global__ __launch_bounds__(256) void zero_agent_k(unsigned long long* __restrict__ out8,
                                                    int n8) {
    int stride = gridDim.x * blockDim.x;
    for (int i = blockIdx.x * blockDim.x + threadIdx.x; i < n8; i += stride)
        __hip_atomic_store(out8 + i, 0ULL, __ATOMIC_RELAXED, __HIP_MEMORY_SCOPE_AGENT);
}

// ---------------- atomic scatter — VERBATIM R6 structure (fast regime) --------
// grid (235, 256): j from blockIdx.x (coalesced x/vs reads), b = blockIdx.y.
// No XCD swizzle. Randomness only in atomic DESTINATIONS — fire-and-forget
// RMWs, no dependent-load chain, immune to the L1-MSHR wall (0.146 lines/cy/CU)
// that pins every gather variant at ~200us.
__global__ __launch_bounds__(256) void scatter_atomic_k(const float* __restrict__ x,
                                                        const int* __restrict__ vs,
                                                        float* __restrict__ out) {
    int j = blockIdx.x * blockDim.x + threadIdx.x;
    int b = blockIdx.y;
    if (j < NSEL_C) {
        int v = vs[j];
        const float* p = x + ((size_t)b * NSEL_C + j) * 3;
        float* q = out + ((size_t)b * NV_C + v) * 3;
        atomicAdd(q + 0, p[0]);
        atomicAdd(q + 1, p[1]);
        atomicAdd(q + 2, p[2]);
    }
}

extern "C" void kernel_launch(void* const* d_in, const int* in_sizes, int n_in,
                              void* d_out, int out_size, void* d_ws, size_t ws_size,
                              hipStream_t stream) {
    const float* x  = (const float*)d_in[0];
    const int*   vs = (const int*)d_in[1];
    float* out = (float*)d_out;

    // 1) zero the output via MALL-allocating agent-scope 8B stores.
    //    out_size = 76.8M floats -> 38.4M u64 (out_size % 2 == 0).
    int n8 = out_size / 2;
    zero_agent_k<<<2048, 256, 0, stream>>>((unsigned long long*)out, n8);

    // 2) atomic scatter-add, R6 grid shape, no swizzle.
    dim3 grid(NBLK_P, B_C);
    scatter_atomic_k<<<grid, 256, 0, stream>>>(x, vs, out);
}

// Round 11
// 299.072 us; speedup vs baseline: 7.6208x; 7.6208x over previous
//
#include <hip/hip_runtime.h>

// Problem constants (from reference): B=256, NSEL=60000, NVERTS=100000, F=3
#define B_C      256
#define NSEL_C   60000
#define NV_C     100000
#define SLICE    (NSEL_C * 3)             // floats per x batch slice
#define OUTSLICE (NV_C * 3)               // floats per out batch slice
#define CHUNK_V  6400                     // verts per LDS chunk (76.8 KB)
#define NCHUNK   16                       // ceil(100000/6400); last chunk = 4000
#define TPB      512
#define NXCD     8

typedef float f32x4 __attribute__((ext_vector_type(4)));
typedef int   i32x4 __attribute__((ext_vector_type(4)));

// One workgroup = (batch b, vertex-chunk c). Zero a CHUNK_V*3-float LDS
// accumulator, stream the ENTIRE x[b] slice + vs with dense coalesced vector
// loads (dense streaming sustains ~0.38 lines/cy/CU vs the 0.147 sparse-read
// wall that pinned every gather variant at ~200us, and fire-and-forget global
// atomics at 2230us after any HIP-side zero), LDS-atomicAdd the rows whose
// vertex falls in this chunk (~1/16), then write the chunk out with coalesced
// f32x4 stores. Randomness only in LDS addressing (banked, ~2-way, free).
// No CSR build, no workspace, no global atomics.
// XCD swizzle: batch b only on XCD b%8 -> its 720 KB slice is fetched from
// HBM once and served to all 16 chunk-workgroups from that XCD's L2
// (concurrently ~4 batches x 720 KB + vs 240 KB < 4 MB).
__global__ __launch_bounds__(TPB) void privsum_k(const float* __restrict__ x,
                                                 const int* __restrict__ vs,
                                                 float* __restrict__ out) {
    __shared__ float acc[CHUNK_V * 3];    // 76.8 KB -> 2 wg/CU

    int lin  = blockIdx.x;                // [0, 4096)
    int xcd  = lin & (NXCD - 1);
    int rest = lin >> 3;                  // [0, 512)
    int c    = rest & (NCHUNK - 1);       // chunk [0,16)
    int b    = (rest >> 4) * NXCD + xcd;  // batch [0,256), bijective
    int vA   = c * CHUNK_V;
    int tid  = threadIdx.x;

    // ---- zero LDS (vec4) ----
    f32x4* acc4 = (f32x4*)acc;
    const int NACC4 = CHUNK_V * 3 / 4;    // 4800
    f32x4 z = {0.f, 0.f, 0.f, 0.f};
    for (int i = tid; i < NACC4; i += TPB) acc4[i] = z;
    __syncthreads();

    // ---- dense stream over all rows, 4 rows per thread-iteration ----
    const float* xb = x + (size_t)b * SLICE;
    for (int j0 = tid * 4; j0 < NSEL_C; j0 += TPB * 4) {
        i32x4 v4 = *(const i32x4*)(vs + j0);            // 16B-aligned
        const f32x4* xp = (const f32x4*)(xb + 3 * (size_t)j0);  // 48B/thread
        f32x4 q0 = xp[0], q1 = xp[1], q2 = xp[2];
        // unpack 4 rows x 3 floats from the 12 contiguous floats
        float r0x = q0.x, r0y = q0.y, r0z = q0.z;
        float r1x = q0.w, r1y = q1.x, r1z = q1.y;
        float r2x = q1.z, r2y = q1.w, r2z = q2.x;
        float r3x = q2.y, r3y = q2.z, r3z = q2.w;
        unsigned d0 = (unsigned)(v4.x - vA);
        unsigned d1 = (unsigned)(v4.y - vA);
        unsigned d2 = (unsigned)(v4.z - vA);
        unsigned d3 = (unsigned)(v4.w - vA);
        if (d0 < CHUNK_V) { int p = d0 * 3;
            atomicAdd(&acc[p], r0x); atomicAdd(&acc[p + 1], r0y); atomicAdd(&acc[p + 2], r0z); }
        if (d1 < CHUNK_V) { int p = d1 * 3;
            atomicAdd(&acc[p], r1x); atomicAdd(&acc[p + 1], r1y); atomicAdd(&acc[p + 2], r1z); }
        if (d2 < CHUNK_V) { int p = d2 * 3;
            atomicAdd(&acc[p], r2x); atomicAdd(&acc[p + 1], r2y); atomicAdd(&acc[p + 2], r2z); }
        if (d3 < CHUNK_V) { int p = d3 * 3;
            atomicAdd(&acc[p], r3x); atomicAdd(&acc[p + 1], r3y); atomicAdd(&acc[p + 2], r3z); }
    }
    __syncthreads();

    // ---- coalesced chunk writeout ----
    int vB  = (vA + CHUNK_V < NV_C) ? vA + CHUNK_V : NV_C;   // last chunk 4000
    int n4  = (vB - vA) * 3 / 4;          // 4800 or 3000, exact
    f32x4* ob = (f32x4*)(out + (size_t)b * OUTSLICE + (size_t)vA * 3);  // 16B-aligned
    for (int i = tid; i < n4; i += TPB) ob[i] = acc4[i];
}

extern "C" void kernel_launch(void* const* d_in, const int* in_sizes, int n_in,
                              void* d_out, int out_size, void* d_ws, size_t ws_size,
                              hipStream_t stream) {
    const float* x  = (const float*)d_in[0];
    const int*   vs = (const int*)d_in[1];
    float* out = (float*)d_out;

    // 256 batches x 16 chunks, XCD-swizzled (4096 % 8 == 0)
    privsum_k<<<B_C * NCHUNK, TPB, 0, stream>>>(x, vs, out);
}